// Round 4
// baseline (1765.455 us; speedup 1.0000x reference)
//
#include <hip/hip_runtime.h>
#include <hip/hip_bf16.h>
#include <stdint.h>

#define NTOK 49

typedef __bf16 bf16x8 __attribute__((ext_vector_type(8)));
typedef float f32x4 __attribute__((ext_vector_type(4)));

__device__ __forceinline__ uint16_t f2bf(float f){
  uint32_t x = __float_as_uint(f);
  uint32_t r = (x + 0x7fffu + ((x >> 16) & 1u)) >> 16;
  return (uint16_t)r;
}

// swizzled 16B read from a 64-wide (128B-stride) LDS tile
#define LDS_LD8(buf, row, kelem) \
  __builtin_bit_cast(bf16x8, *(const uint4*)((const char*)(buf) + (row)*128 + ((((kelem)*2)) ^ ((((row))&7)<<4))))

__global__ void prep_kernel(const float* __restrict__ Wqkv,
                            const float* __restrict__ Wout,
                            const float* __restrict__ btab,
                            const int* __restrict__ ridx,
                            uint16_t* __restrict__ WqkvT,
                            uint16_t* __restrict__ WoutT,
                            float* __restrict__ biasPre){
  const int T1 = 1536*256, T2 = 256*512, T3 = 8*2401;
  for (int i = blockIdx.x*blockDim.x + threadIdx.x; i < T1+T2+T3; i += gridDim.x*blockDim.x){
    if (i < T1){ int n = i/256, k = i%256; WqkvT[i] = f2bf(Wqkv[k*1536 + n]); }
    else if (i < T1+T2){ int j = i - T1; int n = j/512, k = j%512; WoutT[j] = f2bf(Wout[k*256 + n]); }
    else { int j = i - T1 - T2; int h = j/2401, ij = j%2401; biasPre[j] = btab[ridx[ij]*8 + h]; }
  }
}

// LDS: xn 50*256*2=25600, qs/ks/ps 50*64*2=6400 each, vt 64*64*2=8192 -> 52992 B -> 3 blocks/CU
__global__ __launch_bounds__(256, 3)
void maxvit_fused(const float* __restrict__ x,
                  const float* __restrict__ gamma,
                  const float* __restrict__ beta,
                  const uint16_t* __restrict__ WqkvT,   // bf16 [1536][256]
                  const uint16_t* __restrict__ WoutT,   // bf16 [256][512]
                  const float*    __restrict__ bout,    // [256]
                  const float*    __restrict__ biasPre, // [8][49][49]
                  float* __restrict__ out)              // [B][49][256] fp32
{
  __shared__ uint16_t xn[50*256];  // row 49 = zeros; reads of rows>49 clamp to 49
  __shared__ uint16_t qs[50*64];
  __shared__ uint16_t ks[50*64];
  __shared__ uint16_t ps[50*64];   // P, then reused for O_h
  __shared__ uint16_t vt[64*64];   // V transposed: [d][token]

  const int b    = blockIdx.x;
  const int tid  = threadIdx.x;
  const int wave = tid >> 6;
  const int lane = tid & 63;
  const int lo   = lane & 15;
  const int g    = lane >> 4;
  const f32x4 fzero = {0.f, 0.f, 0.f, 0.f};

  // ---------------- LayerNorm (R2-identical math) ----------------
  {
    const int c0 = lane * 4;
    float4 gm = *(const float4*)(gamma + c0);
    float4 bt = *(const float4*)(beta  + c0);
    for (int r = wave; r < 50; r += 4){
      char* dst = (char*)xn + r*512 + ((c0*2) ^ ((r&7)<<4));
      if (r < NTOK){
        float4 u = *(const float4*)(x + ((size_t)(b*NTOK + r))*256 + c0);
        float s  = u.x+u.y+u.z+u.w;
        float ss = u.x*u.x+u.y*u.y+u.z*u.z+u.w*u.w;
        #pragma unroll
        for (int d = 1; d < 64; d <<= 1){ s += __shfl_xor(s, d); ss += __shfl_xor(ss, d); }
        float mu  = s  * (1.0f/256.0f);
        float var = ss * (1.0f/256.0f) - mu*mu;
        float rs  = rsqrtf(var + 1e-5f);
        ushort4 o;
        o.x = f2bf((u.x-mu)*rs*gm.x+bt.x);
        o.y = f2bf((u.y-mu)*rs*gm.y+bt.y);
        o.z = f2bf((u.z-mu)*rs*gm.z+bt.z);
        o.w = f2bf((u.w-mu)*rs*gm.w+bt.w);
        *(ushort4*)dst = o;
      } else {
        ushort4 z; z.x = z.y = z.z = z.w = 0;
        *(ushort4*)dst = z;
      }
    }
  }
  __syncthreads();

  f32x4 outacc[4][4];
  #pragma unroll
  for (int m = 0; m < 4; m++)
    #pragma unroll
    for (int n = 0; n < 4; n++) outacc[m][n] = fzero;

  for (int h = 0; h < 8; ++h){
    // ---------------- QKV projection for head h (R2 orientation) ----------------
    f32x4 aq[4], ak[4], av[4];
    #pragma unroll
    for (int m = 0; m < 4; m++){ aq[m] = fzero; ak[m] = fzero; av[m] = fzero; }
    const uint16_t* pq = WqkvT + (size_t)(       h*64 + wave*16 + lo)*256;
    const uint16_t* pk = WqkvT + (size_t)( 512 + h*64 + wave*16 + lo)*256;
    const uint16_t* pv = WqkvT + (size_t)(1024 + h*64 + wave*16 + lo)*256;
    #pragma unroll
    for (int k0 = 0; k0 < 256; k0 += 32){
      const int kb = k0 + g*8;
      bf16x8 afr[4];
      #pragma unroll
      for (int m = 0; m < 4; m++){
        int row = m*16 + lo;
        if (m == 3) row = (row < 49) ? row : 49;   // xn row 49 = zeros
        afr[m] = __builtin_bit_cast(bf16x8,
          *(const uint4*)((const char*)xn + row*512 + ((kb*2) ^ ((row&7)<<4))));
      }
      bf16x8 fq = __builtin_bit_cast(bf16x8, *(const uint4*)(pq + kb));
      bf16x8 fk = __builtin_bit_cast(bf16x8, *(const uint4*)(pk + kb));
      bf16x8 fv = __builtin_bit_cast(bf16x8, *(const uint4*)(pv + kb));
      #pragma unroll
      for (int m = 0; m < 4; m++){
        aq[m] = __builtin_amdgcn_mfma_f32_16x16x32_bf16(afr[m], fq, aq[m], 0, 0, 0);
        ak[m] = __builtin_amdgcn_mfma_f32_16x16x32_bf16(afr[m], fk, ak[m], 0, 0, 0);
        av[m] = __builtin_amdgcn_mfma_f32_16x16x32_bf16(afr[m], fv, av[m], 0, 0, 0);
      }
    }
    {
      const int d = wave*16 + lo;
      #pragma unroll
      for (int m = 0; m < 4; m++){
        #pragma unroll
        for (int r = 0; r < 4; r++){
          const int token = m*16 + g*4 + r;
          const int tok   = (token < 49) ? token : 49;   // racers write identical values
          *(uint16_t*)((char*)qs + tok*128 + ((d*2) ^ ((tok&7)<<4))) = f2bf(aq[m][r]*0.125f);
          *(uint16_t*)((char*)ks + tok*128 + ((d*2) ^ ((tok&7)<<4))) = f2bf(ak[m][r]);
          *(uint16_t*)((char*)vt + d*128 + ((token*2) ^ ((d&7)<<4))) = f2bf(av[m][r]);
        }
      }
    }
    __syncthreads();   // (i) qs/ks/vt complete

    // ---------------- S = q k^T (+bias, mask) ----------------
    f32x4 s[4];
    #pragma unroll
    for (int n = 0; n < 4; n++) s[n] = fzero;
    {
      int qrow = wave*16 + lo; qrow = (qrow < 49) ? qrow : 49;
      bf16x8 a0 = LDS_LD8(qs, qrow, g*8);
      bf16x8 a1 = LDS_LD8(qs, qrow, 32 + g*8);
      #pragma unroll
      for (int n = 0; n < 4; n++){
        int krow = n*16 + lo;
        if (n == 3) krow = (krow < 49) ? krow : 49;
        bf16x8 b0 = LDS_LD8(ks, krow, g*8);
        bf16x8 b1 = LDS_LD8(ks, krow, 32 + g*8);
        s[n] = __builtin_amdgcn_mfma_f32_16x16x32_bf16(a0, b0, s[n], 0, 0, 0);
        s[n] = __builtin_amdgcn_mfma_f32_16x16x32_bf16(a1, b1, s[n], 0, 0, 0);
      }
    }
    {
      const float* bp = biasPre + h*2401;
      #pragma unroll
      for (int n = 0; n < 4; n++){
        const int j = n*16 + lo;
        #pragma unroll
        for (int r = 0; r < 4; r++){
          const int i = wave*16 + g*4 + r;
          float v = s[n][r];
          if (j < NTOK){ if (i < NTOK) v += bp[i*49 + j]; }
          else v = -1e30f;
          s[n][r] = v;
        }
      }
      // softmax over j: each score row lives in one 16-lane group
      float mx[4], sm[4];
      #pragma unroll
      for (int r = 0; r < 4; r++){
        float m0 = fmaxf(fmaxf(s[0][r], s[1][r]), fmaxf(s[2][r], s[3][r]));
        #pragma unroll
        for (int d = 1; d < 16; d <<= 1) m0 = fmaxf(m0, __shfl_xor(m0, d));
        mx[r] = m0;
        sm[r] = 0.f;
      }
      #pragma unroll
      for (int n = 0; n < 4; n++)
        #pragma unroll
        for (int r = 0; r < 4; r++){ float p = __expf(s[n][r] - mx[r]); s[n][r] = p; sm[r] += p; }
      #pragma unroll
      for (int r = 0; r < 4; r++){
        float t = sm[r];
        #pragma unroll
        for (int d = 1; d < 16; d <<= 1) t += __shfl_xor(t, d);
        sm[r] = 1.0f / t;
      }
      // write P (wave-private strip -> no barrier before PV)
      #pragma unroll
      for (int n = 0; n < 4; n++){
        const int j = n*16 + lo;
        #pragma unroll
        for (int r = 0; r < 4; r++){
          int i = wave*16 + g*4 + r; i = (i < 49) ? i : 49;  // racers identical
          *(uint16_t*)((char*)ps + i*128 + ((j*2) ^ ((i&7)<<4))) = f2bf(s[n][r]*sm[r]);
        }
      }
    }

    // ---------------- O = P V ----------------
    f32x4 o[4];
    #pragma unroll
    for (int n = 0; n < 4; n++) o[n] = fzero;
    {
      int prow = wave*16 + lo; prow = (prow < 49) ? prow : 49;
      bf16x8 a0 = LDS_LD8(ps, prow, g*8);
      bf16x8 a1 = LDS_LD8(ps, prow, 32 + g*8);
      #pragma unroll
      for (int n = 0; n < 4; n++){
        const int vrow = n*16 + lo;
        bf16x8 b0 = LDS_LD8(vt, vrow, g*8);
        bf16x8 b1 = LDS_LD8(vt, vrow, 32 + g*8);
        o[n] = __builtin_amdgcn_mfma_f32_16x16x32_bf16(a0, b0, o[n], 0, 0, 0);
        o[n] = __builtin_amdgcn_mfma_f32_16x16x32_bf16(a1, b1, o[n], 0, 0, 0);
      }
    }
    // write O_h into ps (own strip; own wave already consumed its P rows)
    #pragma unroll
    for (int n = 0; n < 4; n++){
      const int d = n*16 + lo;
      #pragma unroll
      for (int r = 0; r < 4; r++){
        int token = wave*16 + g*4 + r; token = (token < 49) ? token : 49;  // racers identical
        *(uint16_t*)((char*)ps + token*128 + ((d*2) ^ ((token&7)<<4))) = f2bf(o[n][r]);
      }
    }
    __syncthreads();   // (ii) O_h complete (read cross-wave next)

    // ---------------- out-projection accumulate ----------------
    #pragma unroll
    for (int kk = 0; kk < 2; ++kk){
      const int kb = kk*32 + g*8;
      bf16x8 afr[4];
      #pragma unroll
      for (int m = 0; m < 4; m++){
        int row = m*16 + lo;
        if (m == 3) row = (row < 49) ? row : 49;
        afr[m] = LDS_LD8(ps, row, kb);
      }
      #pragma unroll
      for (int n = 0; n < 4; n++){
        const int ncol = wave*64 + n*16 + lo;
        bf16x8 bb = __builtin_bit_cast(bf16x8,
          *(const uint4*)(WoutT + (size_t)ncol*512 + h*64 + kb));
        #pragma unroll
        for (int m = 0; m < 4; m++)
          outacc[m][n] = __builtin_amdgcn_mfma_f32_16x16x32_bf16(afr[m], bb, outacc[m][n], 0, 0, 0);
      }
    }
  }

  // ---------------- epilogue: +b_out, store fp32 (R2-identical) ----------------
  #pragma unroll
  for (int n = 0; n < 4; n++){
    const int col = wave*64 + n*16 + lo;
    const float bo = bout[col];
    #pragma unroll
    for (int m = 0; m < 4; m++){
      #pragma unroll
      for (int r = 0; r < 4; r++){
        const int token = m*16 + g*4 + r;
        if (token < NTOK)
          out[((size_t)(b*NTOK + token))*256 + col] = outacc[m][n][r] + bo;
      }
    }
  }
}

extern "C" void kernel_launch(void* const* d_in, const int* in_sizes, int n_in,
                              void* d_out, int out_size, void* d_ws, size_t ws_size,
                              hipStream_t stream){
  const float* x     = (const float*)d_in[0];
  const float* gamma = (const float*)d_in[1];
  const float* beta  = (const float*)d_in[2];
  const float* Wqkv  = (const float*)d_in[3];
  const float* Wout  = (const float*)d_in[4];
  const float* bout  = (const float*)d_in[5];
  const float* btab  = (const float*)d_in[6];
  const int*   ridx  = (const int*)d_in[7];

  uint16_t* WqkvT   = (uint16_t*)d_ws;                          // 786432 B
  uint16_t* WoutT   = (uint16_t*)((char*)d_ws + 786432);        // 262144 B
  float*    biasPre = (float*)((char*)d_ws + 786432 + 262144);  // 76832 B

  prep_kernel<<<512, 256, 0, stream>>>(Wqkv, Wout, btab, ridx, WqkvT, WoutT, biasPre);
  maxvit_fused<<<4096, 256, 0, stream>>>(x, gamma, beta, WqkvT, WoutT, bout, biasPre,
                                         (float*)d_out);
}

// Round 5
// 1082.972 us; speedup vs baseline: 1.6302x; 1.6302x over previous
//
#include <hip/hip_runtime.h>
#include <hip/hip_bf16.h>
#include <stdint.h>

#define NTOK 49

typedef __bf16 bf16x8 __attribute__((ext_vector_type(8)));
typedef float f32x4 __attribute__((ext_vector_type(4)));

__device__ __forceinline__ uint16_t f2bf(float f){
  uint32_t x = __float_as_uint(f);
  uint32_t r = (x + 0x7fffu + ((x >> 16) & 1u)) >> 16;
  return (uint16_t)r;
}

// swizzled 16B read from a 64-wide (128B-stride) LDS tile
#define LDS_LD8(buf, row, kelem) \
  __builtin_bit_cast(bf16x8, *(const uint4*)((const char*)(buf) + (row)*128 + ((((kelem)*2)) ^ ((((row))&7)<<4))))

__global__ void prep_kernel(const float* __restrict__ Wqkv,
                            const float* __restrict__ Wout,
                            const float* __restrict__ btab,
                            const int* __restrict__ ridx,
                            uint16_t* __restrict__ WqkvT,
                            uint16_t* __restrict__ WoutT,
                            float* __restrict__ biasPre){
  const int T1 = 1536*256, T2 = 256*512, T3 = 8*2401;
  for (int i = blockIdx.x*blockDim.x + threadIdx.x; i < T1+T2+T3; i += gridDim.x*blockDim.x){
    if (i < T1){ int n = i/256, k = i%256; WqkvT[i] = f2bf(Wqkv[k*1536 + n]); }
    else if (i < T1+T2){ int j = i - T1; int n = j/512, k = j%512; WoutT[j] = f2bf(Wout[k*256 + n]); }
    else { int j = i - T1 - T2; int h = j/2401, ij = j%2401; biasPre[j] = btab[ridx[ij]*8 + h]; }
  }
}

// LDS: xn 50*256*2=25600, qs/ks/ps 50*64*2=6400 each, vt 64*64*2=8192 -> 52992 B
// 3 blocks/CU by LDS (3*53248=159744 <= 163840); VGPR ~128 -> 3 waves/SIMD*128=384 <= 512.
// launch_bounds min-waves arg stays 2: capping VGPR for 3 forced spills (R4: FETCH 175MB->1.9GB).
__global__ __launch_bounds__(256, 2)
void maxvit_fused(const float* __restrict__ x,
                  const float* __restrict__ gamma,
                  const float* __restrict__ beta,
                  const uint16_t* __restrict__ WqkvT,   // bf16 [1536][256]
                  const uint16_t* __restrict__ WoutT,   // bf16 [256][512]
                  const float*    __restrict__ bout,    // [256]
                  const float*    __restrict__ biasPre, // [8][49][49]
                  float* __restrict__ out)              // [B][49][256] fp32
{
  __shared__ uint16_t xn[50*256];  // row 49 = zeros; reads of rows>49 clamp to 49
  __shared__ uint16_t qs[50*64];
  __shared__ uint16_t ks[50*64];
  __shared__ uint16_t ps[50*64];   // P, then reused for O_h
  __shared__ uint16_t vt[64*64];   // V transposed: [d][token]

  const int b    = blockIdx.x;
  const int tid  = threadIdx.x;
  const int wave = tid >> 6;
  const int lane = tid & 63;
  const int lo   = lane & 15;
  const int g    = lane >> 4;
  const f32x4 fzero = {0.f, 0.f, 0.f, 0.f};

  // ---------------- LayerNorm (R2-identical math) ----------------
  {
    const int c0 = lane * 4;
    float4 gm = *(const float4*)(gamma + c0);
    float4 bt = *(const float4*)(beta  + c0);
    for (int r = wave; r < 50; r += 4){
      char* dst = (char*)xn + r*512 + ((c0*2) ^ ((r&7)<<4));
      if (r < NTOK){
        float4 u = *(const float4*)(x + ((size_t)(b*NTOK + r))*256 + c0);
        float s  = u.x+u.y+u.z+u.w;
        float ss = u.x*u.x+u.y*u.y+u.z*u.z+u.w*u.w;
        #pragma unroll
        for (int d = 1; d < 64; d <<= 1){ s += __shfl_xor(s, d); ss += __shfl_xor(ss, d); }
        float mu  = s  * (1.0f/256.0f);
        float var = ss * (1.0f/256.0f) - mu*mu;
        float rs  = rsqrtf(var + 1e-5f);
        ushort4 o;
        o.x = f2bf((u.x-mu)*rs*gm.x+bt.x);
        o.y = f2bf((u.y-mu)*rs*gm.y+bt.y);
        o.z = f2bf((u.z-mu)*rs*gm.z+bt.z);
        o.w = f2bf((u.w-mu)*rs*gm.w+bt.w);
        *(ushort4*)dst = o;
      } else {
        ushort4 z; z.x = z.y = z.z = z.w = 0;
        *(ushort4*)dst = z;
      }
    }
  }
  __syncthreads();

  f32x4 outacc[4][4];
  #pragma unroll
  for (int m = 0; m < 4; m++)
    #pragma unroll
    for (int n = 0; n < 4; n++) outacc[m][n] = fzero;

  for (int h = 0; h < 8; ++h){
    // ---------------- QKV projection for head h (R2 orientation) ----------------
    f32x4 aq[4], ak[4], av[4];
    #pragma unroll
    for (int m = 0; m < 4; m++){ aq[m] = fzero; ak[m] = fzero; av[m] = fzero; }
    const uint16_t* pq = WqkvT + (size_t)(       h*64 + wave*16 + lo)*256;
    const uint16_t* pk = WqkvT + (size_t)( 512 + h*64 + wave*16 + lo)*256;
    const uint16_t* pv = WqkvT + (size_t)(1024 + h*64 + wave*16 + lo)*256;
    #pragma unroll
    for (int k0 = 0; k0 < 256; k0 += 32){
      const int kb = k0 + g*8;
      bf16x8 afr[4];
      #pragma unroll
      for (int m = 0; m < 4; m++){
        int row = m*16 + lo;
        if (m == 3) row = (row < 49) ? row : 49;   // xn row 49 = zeros
        afr[m] = __builtin_bit_cast(bf16x8,
          *(const uint4*)((const char*)xn + row*512 + ((kb*2) ^ ((row&7)<<4))));
      }
      bf16x8 fq = __builtin_bit_cast(bf16x8, *(const uint4*)(pq + kb));
      bf16x8 fk = __builtin_bit_cast(bf16x8, *(const uint4*)(pk + kb));
      bf16x8 fv = __builtin_bit_cast(bf16x8, *(const uint4*)(pv + kb));
      #pragma unroll
      for (int m = 0; m < 4; m++){
        aq[m] = __builtin_amdgcn_mfma_f32_16x16x32_bf16(afr[m], fq, aq[m], 0, 0, 0);
        ak[m] = __builtin_amdgcn_mfma_f32_16x16x32_bf16(afr[m], fk, ak[m], 0, 0, 0);
        av[m] = __builtin_amdgcn_mfma_f32_16x16x32_bf16(afr[m], fv, av[m], 0, 0, 0);
      }
    }
    {
      const int d = wave*16 + lo;
      #pragma unroll
      for (int m = 0; m < 4; m++){
        #pragma unroll
        for (int r = 0; r < 4; r++){
          const int token = m*16 + g*4 + r;
          const int tok   = (token < 49) ? token : 49;   // racers write identical values
          *(uint16_t*)((char*)qs + tok*128 + ((d*2) ^ ((tok&7)<<4))) = f2bf(aq[m][r]*0.125f);
          *(uint16_t*)((char*)ks + tok*128 + ((d*2) ^ ((tok&7)<<4))) = f2bf(ak[m][r]);
          *(uint16_t*)((char*)vt + d*128 + ((token*2) ^ ((d&7)<<4))) = f2bf(av[m][r]);
        }
      }
    }
    __syncthreads();   // (i) qs/ks/vt complete

    // ---------------- S = q k^T (+bias, mask) ----------------
    f32x4 s[4];
    #pragma unroll
    for (int n = 0; n < 4; n++) s[n] = fzero;
    {
      int qrow = wave*16 + lo; qrow = (qrow < 49) ? qrow : 49;
      bf16x8 a0 = LDS_LD8(qs, qrow, g*8);
      bf16x8 a1 = LDS_LD8(qs, qrow, 32 + g*8);
      #pragma unroll
      for (int n = 0; n < 4; n++){
        int krow = n*16 + lo;
        if (n == 3) krow = (krow < 49) ? krow : 49;
        bf16x8 b0 = LDS_LD8(ks, krow, g*8);
        bf16x8 b1 = LDS_LD8(ks, krow, 32 + g*8);
        s[n] = __builtin_amdgcn_mfma_f32_16x16x32_bf16(a0, b0, s[n], 0, 0, 0);
        s[n] = __builtin_amdgcn_mfma_f32_16x16x32_bf16(a1, b1, s[n], 0, 0, 0);
      }
    }
    {
      const float* bp = biasPre + h*2401;
      #pragma unroll
      for (int n = 0; n < 4; n++){
        const int j = n*16 + lo;
        #pragma unroll
        for (int r = 0; r < 4; r++){
          const int i = wave*16 + g*4 + r;
          float v = s[n][r];
          if (j < NTOK){ if (i < NTOK) v += bp[i*49 + j]; }
          else v = -1e30f;
          s[n][r] = v;
        }
      }
      // softmax over j: each score row lives in one 16-lane group
      float mx[4], sm[4];
      #pragma unroll
      for (int r = 0; r < 4; r++){
        float m0 = fmaxf(fmaxf(s[0][r], s[1][r]), fmaxf(s[2][r], s[3][r]));
        #pragma unroll
        for (int d = 1; d < 16; d <<= 1) m0 = fmaxf(m0, __shfl_xor(m0, d));
        mx[r] = m0;
        sm[r] = 0.f;
      }
      #pragma unroll
      for (int n = 0; n < 4; n++)
        #pragma unroll
        for (int r = 0; r < 4; r++){ float p = __expf(s[n][r] - mx[r]); s[n][r] = p; sm[r] += p; }
      #pragma unroll
      for (int r = 0; r < 4; r++){
        float t = sm[r];
        #pragma unroll
        for (int d = 1; d < 16; d <<= 1) t += __shfl_xor(t, d);
        sm[r] = 1.0f / t;
      }
      // write P (wave-private strip -> no barrier before PV)
      #pragma unroll
      for (int n = 0; n < 4; n++){
        const int j = n*16 + lo;
        #pragma unroll
        for (int r = 0; r < 4; r++){
          int i = wave*16 + g*4 + r; i = (i < 49) ? i : 49;  // racers identical
          *(uint16_t*)((char*)ps + i*128 + ((j*2) ^ ((i&7)<<4))) = f2bf(s[n][r]*sm[r]);
        }
      }
    }

    // ---------------- O = P V ----------------
    f32x4 o[4];
    #pragma unroll
    for (int n = 0; n < 4; n++) o[n] = fzero;
    {
      int prow = wave*16 + lo; prow = (prow < 49) ? prow : 49;
      bf16x8 a0 = LDS_LD8(ps, prow, g*8);
      bf16x8 a1 = LDS_LD8(ps, prow, 32 + g*8);
      #pragma unroll
      for (int n = 0; n < 4; n++){
        const int vrow = n*16 + lo;
        bf16x8 b0 = LDS_LD8(vt, vrow, g*8);
        bf16x8 b1 = LDS_LD8(vt, vrow, 32 + g*8);
        o[n] = __builtin_amdgcn_mfma_f32_16x16x32_bf16(a0, b0, o[n], 0, 0, 0);
        o[n] = __builtin_amdgcn_mfma_f32_16x16x32_bf16(a1, b1, o[n], 0, 0, 0);
      }
    }
    // write O_h into ps (own strip; own wave already consumed its P rows)
    #pragma unroll
    for (int n = 0; n < 4; n++){
      const int d = n*16 + lo;
      #pragma unroll
      for (int r = 0; r < 4; r++){
        int token = wave*16 + g*4 + r; token = (token < 49) ? token : 49;  // racers identical
        *(uint16_t*)((char*)ps + token*128 + ((d*2) ^ ((token&7)<<4))) = f2bf(o[n][r]);
      }
    }
    __syncthreads();   // (ii) O_h complete (read cross-wave next)

    // ---------------- out-projection accumulate ----------------
    #pragma unroll
    for (int kk = 0; kk < 2; ++kk){
      const int kb = kk*32 + g*8;
      bf16x8 afr[4];
      #pragma unroll
      for (int m = 0; m < 4; m++){
        int row = m*16 + lo;
        if (m == 3) row = (row < 49) ? row : 49;
        afr[m] = LDS_LD8(ps, row, kb);
      }
      #pragma unroll
      for (int n = 0; n < 4; n++){
        const int ncol = wave*64 + n*16 + lo;
        bf16x8 bb = __builtin_bit_cast(bf16x8,
          *(const uint4*)(WoutT + (size_t)ncol*512 + h*64 + kb));
        #pragma unroll
        for (int m = 0; m < 4; m++)
          outacc[m][n] = __builtin_amdgcn_mfma_f32_16x16x32_bf16(afr[m], bb, outacc[m][n], 0, 0, 0);
      }
    }
  }

  // ---------------- epilogue: +b_out, store fp32 (R2-identical) ----------------
  #pragma unroll
  for (int n = 0; n < 4; n++){
    const int col = wave*64 + n*16 + lo;
    const float bo = bout[col];
    #pragma unroll
    for (int m = 0; m < 4; m++){
      #pragma unroll
      for (int r = 0; r < 4; r++){
        const int token = m*16 + g*4 + r;
        if (token < NTOK)
          out[((size_t)(b*NTOK + token))*256 + col] = outacc[m][n][r] + bo;
      }
    }
  }
}

extern "C" void kernel_launch(void* const* d_in, const int* in_sizes, int n_in,
                              void* d_out, int out_size, void* d_ws, size_t ws_size,
                              hipStream_t stream){
  const float* x     = (const float*)d_in[0];
  const float* gamma = (const float*)d_in[1];
  const float* beta  = (const float*)d_in[2];
  const float* Wqkv  = (const float*)d_in[3];
  const float* Wout  = (const float*)d_in[4];
  const float* bout  = (const float*)d_in[5];
  const float* btab  = (const float*)d_in[6];
  const int*   ridx  = (const int*)d_in[7];

  uint16_t* WqkvT   = (uint16_t*)d_ws;                          // 786432 B
  uint16_t* WoutT   = (uint16_t*)((char*)d_ws + 786432);        // 262144 B
  float*    biasPre = (float*)((char*)d_ws + 786432 + 262144);  // 76832 B

  prep_kernel<<<512, 256, 0, stream>>>(Wqkv, Wout, btab, ridx, WqkvT, WoutT, biasPre);
  maxvit_fused<<<4096, 256, 0, stream>>>(x, gamma, beta, WqkvT, WoutT, bout, biasPre,
                                         (float*)d_out);
}

// Round 6
// 870.463 us; speedup vs baseline: 2.0282x; 1.2441x over previous
//
#include <hip/hip_runtime.h>
#include <hip/hip_bf16.h>
#include <stdint.h>

#define NTOK 49

typedef __bf16 bf16x8 __attribute__((ext_vector_type(8)));
typedef float f32x4 __attribute__((ext_vector_type(4)));

__device__ __forceinline__ uint16_t f2bf(float f){
  uint32_t x = __float_as_uint(f);
  uint32_t r = (x + 0x7fffu + ((x >> 16) & 1u)) >> 16;
  return (uint16_t)r;
}

// swizzled 16B read from a 64-wide (128B-stride) LDS tile
#define LDS_LD8(buf, row, kelem) \
  __builtin_bit_cast(bf16x8, *(const uint4*)((const char*)(buf) + (row)*128 + ((((kelem)*2)) ^ ((((row))&7)<<4))))

__global__ void prep_kernel(const float* __restrict__ Wqkv,
                            const float* __restrict__ Wout,
                            const float* __restrict__ btab,
                            const int* __restrict__ ridx,
                            uint16_t* __restrict__ WqkvT,
                            uint16_t* __restrict__ WoutT,
                            float* __restrict__ biasPre){
  const int T1 = 1536*256, T2 = 256*512, T3 = 8*2401;
  for (int i = blockIdx.x*blockDim.x + threadIdx.x; i < T1+T2+T3; i += gridDim.x*blockDim.x){
    if (i < T1){ int n = i/256, k = i%256; WqkvT[i] = f2bf(Wqkv[k*1536 + n]); }
    else if (i < T1+T2){ int j = i - T1; int n = j/512, k = j%512; WoutT[j] = f2bf(Wout[k*256 + n]); }
    else { int j = i - T1 - T2; int h = j/2401, ij = j%2401; biasPre[j] = btab[ridx[ij]*8 + h]; }
  }
}

// LDS: xn 25600 + qs 2*6400 + ks 2*6400 + vt 2*8192 + ps 6400 + os 6400 = 80384 B
// -> 2 blocks/CU by LDS. Regs ~128 VGPR + 64 AGPR = 192 -> 2 waves/SIMD (hard cap; 3 needs <=170).
__global__ __launch_bounds__(256, 2)
void maxvit_fused(const float* __restrict__ x,
                  const float* __restrict__ gamma,
                  const float* __restrict__ beta,
                  const uint16_t* __restrict__ WqkvT,   // bf16 [1536][256]
                  const uint16_t* __restrict__ WoutT,   // bf16 [256][512]
                  const float*    __restrict__ bout,    // [256]
                  const float*    __restrict__ biasPre, // [8][49][49]
                  float* __restrict__ out)              // [B][49][256] fp32
{
  __shared__ uint16_t xn[50*256];     // row 49 = zeros; reads of rows>49 clamp to 49
  __shared__ uint16_t qs[2][50*64];   // double-buffered per head
  __shared__ uint16_t ks[2][50*64];
  __shared__ uint16_t vt[2][64*64];   // V transposed: [d][token]
  __shared__ uint16_t ps[50*64];      // P (wave-private strips)
  __shared__ uint16_t os[50*64];      // O_h (written A, read B)

  const int b    = blockIdx.x;
  const int tid  = threadIdx.x;
  const int wave = tid >> 6;
  const int lane = tid & 63;
  const int lo   = lane & 15;
  const int g    = lane >> 4;
  const f32x4 fzero = {0.f, 0.f, 0.f, 0.f};

  // ---------------- LayerNorm (proven R2/R5 math) ----------------
  {
    const int c0 = lane * 4;
    float4 gm = *(const float4*)(gamma + c0);
    float4 bt = *(const float4*)(beta  + c0);
    for (int r = wave; r < 50; r += 4){
      char* dst = (char*)xn + r*512 + ((c0*2) ^ ((r&7)<<4));
      if (r < NTOK){
        float4 u = *(const float4*)(x + ((size_t)(b*NTOK + r))*256 + c0);
        float s  = u.x+u.y+u.z+u.w;
        float ss = u.x*u.x+u.y*u.y+u.z*u.z+u.w*u.w;
        #pragma unroll
        for (int d = 1; d < 64; d <<= 1){ s += __shfl_xor(s, d); ss += __shfl_xor(ss, d); }
        float mu  = s  * (1.0f/256.0f);
        float var = ss * (1.0f/256.0f) - mu*mu;
        float rs  = rsqrtf(var + 1e-5f);
        ushort4 o;
        o.x = f2bf((u.x-mu)*rs*gm.x+bt.x);
        o.y = f2bf((u.y-mu)*rs*gm.y+bt.y);
        o.z = f2bf((u.z-mu)*rs*gm.z+bt.z);
        o.w = f2bf((u.w-mu)*rs*gm.w+bt.w);
        *(ushort4*)dst = o;
      } else {
        ushort4 z; z.x = z.y = z.z = z.w = 0;
        *(ushort4*)dst = z;
      }
    }
  }
  __syncthreads();

  f32x4 outacc[4][4];
  #pragma unroll
  for (int m = 0; m < 4; m++)
    #pragma unroll
    for (int n = 0; n < 4; n++) outacc[m][n] = fzero;

  // -------- helper: Q,K projection for head hh into buffer bi --------
  auto projQK = [&](int hh, int bi){
    f32x4 aq[4], ak[4];
    #pragma unroll
    for (int m = 0; m < 4; m++){ aq[m] = fzero; ak[m] = fzero; }
    const uint16_t* pq = WqkvT + (size_t)(       hh*64 + wave*16 + lo)*256;
    const uint16_t* pk = WqkvT + (size_t)( 512 + hh*64 + wave*16 + lo)*256;
    #pragma unroll
    for (int k0 = 0; k0 < 256; k0 += 32){
      const int kb = k0 + g*8;
      bf16x8 afr[4];
      #pragma unroll
      for (int m = 0; m < 4; m++){
        int row = m*16 + lo;
        if (m == 3) row = (row < 49) ? row : 49;   // xn row 49 = zeros
        afr[m] = __builtin_bit_cast(bf16x8,
          *(const uint4*)((const char*)xn + row*512 + ((kb*2) ^ ((row&7)<<4))));
      }
      bf16x8 fq = __builtin_bit_cast(bf16x8, *(const uint4*)(pq + kb));
      bf16x8 fk = __builtin_bit_cast(bf16x8, *(const uint4*)(pk + kb));
      #pragma unroll
      for (int m = 0; m < 4; m++){
        aq[m] = __builtin_amdgcn_mfma_f32_16x16x32_bf16(afr[m], fq, aq[m], 0, 0, 0);
        ak[m] = __builtin_amdgcn_mfma_f32_16x16x32_bf16(afr[m], fk, ak[m], 0, 0, 0);
      }
    }
    uint16_t* qb = qs[bi];
    uint16_t* kb2 = ks[bi];
    const int d = wave*16 + lo;
    #pragma unroll
    for (int m = 0; m < 4; m++){
      #pragma unroll
      for (int r = 0; r < 4; r++){
        const int token = m*16 + g*4 + r;
        const int tok   = (token < 49) ? token : 49;   // racers write identical values
        *(uint16_t*)((char*)qb  + tok*128 + ((d*2) ^ ((tok&7)<<4))) = f2bf(aq[m][r]*0.125f);
        *(uint16_t*)((char*)kb2 + tok*128 + ((d*2) ^ ((tok&7)<<4))) = f2bf(ak[m][r]);
      }
    }
  };

  // -------- helper: V projection for head hh into buffer bi --------
  auto projV = [&](int hh, int bi){
    f32x4 av[4];
    #pragma unroll
    for (int m = 0; m < 4; m++) av[m] = fzero;
    const uint16_t* pv = WqkvT + (size_t)(1024 + hh*64 + wave*16 + lo)*256;
    #pragma unroll
    for (int k0 = 0; k0 < 256; k0 += 32){
      const int kb = k0 + g*8;
      bf16x8 afr[4];
      #pragma unroll
      for (int m = 0; m < 4; m++){
        int row = m*16 + lo;
        if (m == 3) row = (row < 49) ? row : 49;
        afr[m] = __builtin_bit_cast(bf16x8,
          *(const uint4*)((const char*)xn + row*512 + ((kb*2) ^ ((row&7)<<4))));
      }
      bf16x8 fv = __builtin_bit_cast(bf16x8, *(const uint4*)(pv + kb));
      #pragma unroll
      for (int m = 0; m < 4; m++)
        av[m] = __builtin_amdgcn_mfma_f32_16x16x32_bf16(afr[m], fv, av[m], 0, 0, 0);
    }
    uint16_t* vb = vt[bi];
    const int d = wave*16 + lo;
    #pragma unroll
    for (int m = 0; m < 4; m++){
      #pragma unroll
      for (int r = 0; r < 4; r++){
        const int token = m*16 + g*4 + r;
        *(uint16_t*)((char*)vb + d*128 + ((token*2) ^ ((d&7)<<4))) = f2bf(av[m][r]);
      }
    }
  };

  // ---------------- prologue: head 0 QKV ----------------
  projQK(0, 0);
  projV(0, 0);
  __syncthreads();

  for (int h = 0; h < 8; ++h){
    const int cur = h & 1, nxt = cur ^ 1;
    const uint16_t* qsc = qs[cur];
    const uint16_t* ksc = ks[cur];
    const uint16_t* vtc = vt[cur];

    // ===== Phase A: QK-proj(h+1)  ||  attention(h) =====
    if (h < 7) projQK(h+1, nxt);

    // ---- S = q k^T (+bias, mask) ----
    f32x4 s[4];
    #pragma unroll
    for (int n = 0; n < 4; n++) s[n] = fzero;
    {
      int qrow = wave*16 + lo; qrow = (qrow < 49) ? qrow : 49;
      bf16x8 a0 = LDS_LD8(qsc, qrow, g*8);
      bf16x8 a1 = LDS_LD8(qsc, qrow, 32 + g*8);
      #pragma unroll
      for (int n = 0; n < 4; n++){
        int krow = n*16 + lo;
        if (n == 3) krow = (krow < 49) ? krow : 49;
        bf16x8 b0 = LDS_LD8(ksc, krow, g*8);
        bf16x8 b1 = LDS_LD8(ksc, krow, 32 + g*8);
        s[n] = __builtin_amdgcn_mfma_f32_16x16x32_bf16(a0, b0, s[n], 0, 0, 0);
        s[n] = __builtin_amdgcn_mfma_f32_16x16x32_bf16(a1, b1, s[n], 0, 0, 0);
      }
    }
    {
      const float* bp = biasPre + h*2401;
      #pragma unroll
      for (int n = 0; n < 4; n++){
        const int j = n*16 + lo;
        #pragma unroll
        for (int r = 0; r < 4; r++){
          const int i = wave*16 + g*4 + r;
          float v = s[n][r];
          if (j < NTOK){ if (i < NTOK) v += bp[i*49 + j]; }
          else v = -1e30f;
          s[n][r] = v;
        }
      }
      // softmax over j (rows live in 16-lane groups)
      float mx[4], sm[4];
      #pragma unroll
      for (int r = 0; r < 4; r++){
        float m0 = fmaxf(fmaxf(s[0][r], s[1][r]), fmaxf(s[2][r], s[3][r]));
        #pragma unroll
        for (int d = 1; d < 16; d <<= 1) m0 = fmaxf(m0, __shfl_xor(m0, d));
        mx[r] = m0;
        sm[r] = 0.f;
      }
      #pragma unroll
      for (int n = 0; n < 4; n++)
        #pragma unroll
        for (int r = 0; r < 4; r++){ float p = __expf(s[n][r] - mx[r]); s[n][r] = p; sm[r] += p; }
      #pragma unroll
      for (int r = 0; r < 4; r++){
        float t = sm[r];
        #pragma unroll
        for (int d = 1; d < 16; d <<= 1) t += __shfl_xor(t, d);
        sm[r] = 1.0f / t;
      }
      // write P (wave-private strip)
      #pragma unroll
      for (int n = 0; n < 4; n++){
        const int j = n*16 + lo;
        #pragma unroll
        for (int r = 0; r < 4; r++){
          int i = wave*16 + g*4 + r; i = (i < 49) ? i : 49;  // racers identical
          *(uint16_t*)((char*)ps + i*128 + ((j*2) ^ ((i&7)<<4))) = f2bf(s[n][r]*sm[r]);
        }
      }
    }

    // ---- O = P V ----
    f32x4 o[4];
    #pragma unroll
    for (int n = 0; n < 4; n++) o[n] = fzero;
    {
      int prow = wave*16 + lo; prow = (prow < 49) ? prow : 49;
      bf16x8 a0 = LDS_LD8(ps, prow, g*8);
      bf16x8 a1 = LDS_LD8(ps, prow, 32 + g*8);
      #pragma unroll
      for (int n = 0; n < 4; n++){
        const int vrow = n*16 + lo;
        bf16x8 b0 = LDS_LD8(vtc, vrow, g*8);
        bf16x8 b1 = LDS_LD8(vtc, vrow, 32 + g*8);
        o[n] = __builtin_amdgcn_mfma_f32_16x16x32_bf16(a0, b0, o[n], 0, 0, 0);
        o[n] = __builtin_amdgcn_mfma_f32_16x16x32_bf16(a1, b1, o[n], 0, 0, 0);
      }
    }
    // write O_h into os (wave-private token strip)
    #pragma unroll
    for (int n = 0; n < 4; n++){
      const int d = n*16 + lo;
      #pragma unroll
      for (int r = 0; r < 4; r++){
        int token = wave*16 + g*4 + r; token = (token < 49) ? token : 49;  // racers identical
        *(uint16_t*)((char*)os + token*128 + ((d*2) ^ ((token&7)<<4))) = f2bf(o[n][r]);
      }
    }
    __syncthreads();   // barrier1: os + buf[nxt] q/k complete

    // ===== Phase B: out-proj(h)  ||  V-proj(h+1) =====
    if (h < 7) projV(h+1, nxt);

    #pragma unroll
    for (int kk = 0; kk < 2; ++kk){
      const int kb = kk*32 + g*8;
      bf16x8 afr[4];
      #pragma unroll
      for (int m = 0; m < 4; m++){
        int row = m*16 + lo;
        if (m == 3) row = (row < 49) ? row : 49;
        afr[m] = LDS_LD8(os, row, kb);
      }
      #pragma unroll
      for (int n = 0; n < 4; n++){
        const int ncol = wave*64 + n*16 + lo;
        bf16x8 bb = __builtin_bit_cast(bf16x8,
          *(const uint4*)(WoutT + (size_t)ncol*512 + h*64 + kb));
        #pragma unroll
        for (int m = 0; m < 4; m++)
          outacc[m][n] = __builtin_amdgcn_mfma_f32_16x16x32_bf16(afr[m], bb, outacc[m][n], 0, 0, 0);
      }
    }
    __syncthreads();   // barrier2: os reads done, vt[nxt] complete
  }

  // ---------------- epilogue: +b_out, store fp32 ----------------
  #pragma unroll
  for (int n = 0; n < 4; n++){
    const int col = wave*64 + n*16 + lo;
    const float bo = bout[col];
    #pragma unroll
    for (int m = 0; m < 4; m++){
      #pragma unroll
      for (int r = 0; r < 4; r++){
        const int token = m*16 + g*4 + r;
        if (token < NTOK)
          out[((size_t)(b*NTOK + token))*256 + col] = outacc[m][n][r] + bo;
      }
    }
  }
}

extern "C" void kernel_launch(void* const* d_in, const int* in_sizes, int n_in,
                              void* d_out, int out_size, void* d_ws, size_t ws_size,
                              hipStream_t stream){
  const float* x     = (const float*)d_in[0];
  const float* gamma = (const float*)d_in[1];
  const float* beta  = (const float*)d_in[2];
  const float* Wqkv  = (const float*)d_in[3];
  const float* Wout  = (const float*)d_in[4];
  const float* bout  = (const float*)d_in[5];
  const float* btab  = (const float*)d_in[6];
  const int*   ridx  = (const int*)d_in[7];

  uint16_t* WqkvT   = (uint16_t*)d_ws;                          // 786432 B
  uint16_t* WoutT   = (uint16_t*)((char*)d_ws + 786432);        // 262144 B
  float*    biasPre = (float*)((char*)d_ws + 786432 + 262144);  // 76832 B

  prep_kernel<<<512, 256, 0, stream>>>(Wqkv, Wout, btab, ridx, WqkvT, WoutT, biasPre);
  maxvit_fused<<<4096, 256, 0, stream>>>(x, gamma, beta, WqkvT, WoutT, bout, biasPre,
                                         (float*)d_out);
}